// Round 19
// baseline (432.215 us; speedup 1.0000x reference)
//
#include <hip/hip_runtime.h>
#include <math.h>

// ---------------------------------------------------------------------------
// KGAT-hake, round 19: gemm L0 i-range processed in 32-dim QUARTERS (LDS
// ~19KB -> 8 blocks/CU; accumulators carry across quarters). Rest = round 18
// (best: 427us; att_gather at its random-gather latency floor, grid 2048).
// N=100000 nodes, E=1000000 edges, R=40 rels, out = N x 240 fp32.
// ---------------------------------------------------------------------------

__global__ void hist_kernel(const int* __restrict__ dst, int* __restrict__ cnt,
                            int nedges) {
    int e = blockIdx.x * blockDim.x + threadIdx.x;
    if (e < nedges) atomicAdd(&cnt[dst[e]], 1);
}

// Per-block inclusive scan of cnt -> rowptr[i+1] (block-local) + block sums.
__global__ __launch_bounds__(1024) void scan_block_kernel(
    const int* __restrict__ cnt, int* __restrict__ rowptr,
    int* __restrict__ bsum, int n) {
    __shared__ int swv[16];
    int tid = threadIdx.x, lane = tid & 63, wid = tid >> 6;
    int i = blockIdx.x * 1024 + tid;
    int v = (i < n) ? cnt[i] : 0;
    #pragma unroll
    for (int off = 1; off < 64; off <<= 1) {
        int t = __shfl_up(v, off, 64);
        if (lane >= off) v += t;
    }
    if (lane == 63) swv[wid] = v;
    __syncthreads();
    if (wid == 0) {
        int s = (lane < 16) ? swv[lane] : 0;
        #pragma unroll
        for (int off = 1; off < 16; off <<= 1) {
            int t = __shfl_up(s, off, 64);
            if (lane >= off) s += t;
        }
        if (lane < 16) swv[lane] = s;
    }
    __syncthreads();
    int offv = wid ? swv[wid - 1] : 0;
    if (i < n) rowptr[i + 1] = v + offv;
    if (tid == 1023) bsum[blockIdx.x] = v + offv;
}

// Exclusive scan of up to 128 block sums (one wave, 2 elems/lane).
__global__ __launch_bounds__(64) void scan_tops_kernel(
    const int* __restrict__ bsum, int* __restrict__ boff, int nb) {
    int l = threadIdx.x;
    int a = (2 * l < nb) ? bsum[2 * l] : 0;
    int b = (2 * l + 1 < nb) ? bsum[2 * l + 1] : 0;
    int s = a + b;
    #pragma unroll
    for (int off = 1; off < 64; off <<= 1) {
        int t = __shfl_up(s, off, 64);
        if (l >= off) s += t;
    }
    int excl = s - (a + b);
    if (2 * l < nb) boff[2 * l] = excl;
    if (2 * l + 1 < nb) boff[2 * l + 1] = excl + a;
}

__global__ __launch_bounds__(1024) void scan_add_kernel(
    int* __restrict__ rowptr, const int* __restrict__ boff, int n) {
    int i = blockIdx.x * 1024 + threadIdx.x;
    if (i < n) rowptr[i + 1] += boff[blockIdx.x];
    if (i == 0) rowptr[0] = 0;
}

// Scatter packed src|etype<<17 into dst-sorted CSR slots.
__global__ void fill_kernel(const int* __restrict__ src, const int* __restrict__ dst,
                            const int* __restrict__ etype,
                            const int* __restrict__ rowptr, int* __restrict__ cursor,
                            int* __restrict__ se_s, int nedges) {
    int e = blockIdx.x * blockDim.x + threadIdx.x;
    if (e >= nedges) return;
    int d = dst[e];
    int slot = rowptr[d] + atomicAdd(&cursor[d], 1);
    se_s[slot] = src[e] | (etype[e] << 17);
}

// Fused: HAKE scores + softmax accumulation + layer-0 gather.
// Block: 512 threads; rel coefficients in LDS (stride 196). 8 waves
// grid-stride over nodes; 4 edges/iter x 16 lanes/edge, 2-deep software
// pipeline: group k0+4's t-row loads issue before group k0's compute.
__global__ __launch_bounds__(512) void att_gather_kernel(
    const float* __restrict__ embed, const float* __restrict__ rel,
    const float* __restrict__ pw, const float* __restrict__ mw,
    const int* __restrict__ se_s, const int* __restrict__ rowptr,
    float* __restrict__ att_s, float* __restrict__ ai,
    float* __restrict__ Nh, int nnodes, int nrel)
{
    __shared__ float sRel[40 * 196];
    int tid = threadIdx.x;

    // stage A=|mr|+clamp(br), B=1-clamp(br), P=pr into LDS
    for (int idx = tid; idx < nrel * 64; idx += 512) {
        int r = idx >> 6, d = idx & 63;
        float pr = rel[r * 192 + d];
        float mr = fabsf(rel[r * 192 + 64 + d]);
        float br = rel[r * 192 + 128 + d];
        br = fminf(br, 1.0f);
        br = fmaxf(br, -mr);
        sRel[r * 196 + d]       = mr + br;     // A
        sRel[r * 196 + 64 + d]  = 1.0f - br;   // B
        sRel[r * 196 + 128 + d] = pr;          // P
    }
    __syncthreads();

    const float K = (float)(0.5 * 3.1415926235897933 / 0.21875);  // PI/(2*EMB_RANGE)
    float mwv = mw[0], pwv = pw[0];

    int wave = tid >> 6, lane = tid & 63;
    int g = lane >> 4;            // edge group (4)
    int q = lane & 15;            // dim-slice (16)

    for (int v = blockIdx.x * 8 + wave; v < nnodes; v += gridDim.x * 8) {
        int vu = __builtin_amdgcn_readfirstlane(v);   // scalar node index
        int beg = rowptr[vu];
        int deg = rowptr[vu + 1] - beg;

        const float* hrow = embed + (size_t)vu * 128;
        float4 hp = *(const float4*)(hrow + 4 * q);
        float4 hm = *(const float4*)(hrow + 64 + 4 * q);

        float den = 0.0f;
        float4 accp = make_float4(0.f, 0.f, 0.f, 0.f);
        float4 accm = make_float4(0.f, 0.f, 0.f, 0.f);

        for (int kb = 0; kb < deg; kb += 64) {
            int kchunk = min(64, deg - kb);
            int sev = (lane < kchunk) ? se_s[beg + kb + lane] : 0;  // coalesced

            // ---- pipeline prologue: prefetch group 0 ----
            bool valid0 = g < kchunk;
            int se0 = __shfl(sev, valid0 ? g : 0, 64);
            int r0 = se0 >> 17;
            const float* trow0 = embed + (size_t)(se0 & 0x1FFFF) * 128;
            float4 tp0 = *(const float4*)(trow0 + 4 * q);
            float4 tm0 = *(const float4*)(trow0 + 64 + 4 * q);

            for (int k0 = 0; k0 < kchunk; k0 += 4) {
                // ---- issue next group's loads (independent of compute) ----
                float4 tp1 = tp0, tm1 = tm0;
                int r1 = r0;
                bool valid1 = false;
                if (k0 + 4 < kchunk) {
                    int kn = k0 + 4 + g;
                    valid1 = kn < kchunk;
                    int se1 = __shfl(sev, valid1 ? kn : 0, 64);
                    r1 = se1 >> 17;
                    const float* trow1 = embed + (size_t)(se1 & 0x1FFFF) * 128;
                    tp1 = *(const float4*)(trow1 + 4 * q);
                    tm1 = *(const float4*)(trow1 + 64 + 4 * q);
                }

                // ---- compute current group (tp0/tm0/r0/valid0) ----
                const float* rrow = sRel + r0 * 196;
                float4 A4 = *(const float4*)(rrow + 4 * q);
                float4 B4 = *(const float4*)(rrow + 64 + 4 * q);
                float4 P4 = *(const float4*)(rrow + 128 + 4 * q);

                float pp;
                pp  = fabsf(__sinf((hp.x + P4.x - tp0.x) * K));
                pp += fabsf(__sinf((hp.y + P4.y - tp0.y) * K));
                pp += fabsf(__sinf((hp.z + P4.z - tp0.z) * K));
                pp += fabsf(__sinf((hp.w + P4.w - tp0.w) * K));

                float d0 = hm.x * A4.x - tm0.x * B4.x;
                float d1 = hm.y * A4.y - tm0.y * B4.y;
                float d2 = hm.z * A4.z - tm0.z * B4.z;
                float d3 = hm.w * A4.w - tm0.w * B4.w;
                float qq = (d0 * d0 + d1 * d1) + (d2 * d2 + d3 * d3);

                // reduce pp,qq within the 16-lane group
                #pragma unroll
                for (int off = 1; off < 16; off <<= 1) {
                    pp += __shfl_xor(pp, off, 64);
                    qq += __shfl_xor(qq, off, 64);
                }
                float s = sqrtf(qq) * mwv + pp * pwv;
                float w = valid0 ? __expf(s) : 0.0f;   // s bounded -> no max
                den += w;
                accp.x = fmaf(w, tp0.x, accp.x); accp.y = fmaf(w, tp0.y, accp.y);
                accp.z = fmaf(w, tp0.z, accp.z); accp.w = fmaf(w, tp0.w, accp.w);
                accm.x = fmaf(w, tm0.x, accm.x); accm.y = fmaf(w, tm0.y, accm.y);
                accm.z = fmaf(w, tm0.z, accm.z); accm.w = fmaf(w, tm0.w, accm.w);
                if (valid0 && q == 0) att_s[beg + kb + k0 + g] = w;

                // ---- rotate pipeline ----
                tp0 = tp1; tm0 = tm1; r0 = r1; valid0 = valid1;
            }
        }

        // combine the 4 groups (lane bits 4,5)
        #pragma unroll
        for (int off = 16; off < 64; off <<= 1) {
            accp.x += __shfl_xor(accp.x, off, 64);
            accp.y += __shfl_xor(accp.y, off, 64);
            accp.z += __shfl_xor(accp.z, off, 64);
            accp.w += __shfl_xor(accp.w, off, 64);
            accm.x += __shfl_xor(accm.x, off, 64);
            accm.y += __shfl_xor(accm.y, off, 64);
            accm.z += __shfl_xor(accm.z, off, 64);
            accm.w += __shfl_xor(accm.w, off, 64);
            den += __shfl_xor(den, off, 64);
        }
        float invd = (deg > 0) ? 1.0f / den : 0.0f;
        if (g == 0) {
            float* pn = Nh + (size_t)vu * 128;
            *(float4*)(pn + 4 * q) = make_float4(accp.x * invd, accp.y * invd,
                                                 accp.z * invd, accp.w * invd);
            *(float4*)(pn + 64 + 4 * q) = make_float4(accm.x * invd, accm.y * invd,
                                                      accm.z * invd, accm.w * invd);
            if (q == 0) ai[vu] = invd;
        }
    }
}

// Fused layer 1/2: CSR gather (phase A, wave-per-node, 8 nodes/wave) writes
// x1=(x+Nh), x2=(x*Nh) directly into LDS; phase B = dual GEMV (8-way j-split,
// W via s_load) + leaky_relu + row-normalize. No Nh intermediate.
template<int DIN, int DOUT>
__global__ __launch_bounds__(512) void fused_layer_kernel(
    const float* __restrict__ node, int nstride, const float* __restrict__ nrm_in,
    const float* __restrict__ att_s, const int* __restrict__ se_s,
    const int* __restrict__ rowptr, const float* __restrict__ ai,
    const float* __restrict__ W1, const float* __restrict__ b1,
    const float* __restrict__ W2, const float* __restrict__ b2,
    float* __restrict__ out, int out_col, float* __restrict__ nrm_out, int nnodes)
{
    constexpr int XS  = DIN + 1;     // padded LDS row stride (odd)
    constexpr int LPE = DIN / 4;     // lanes per edge row
    constexpr int EP  = 64 / LPE;    // edges in parallel
    constexpr int U   = 4;           // gather unroll depth
    constexpr int DH  = DOUT / 8;    // j-range per wave
    __shared__ float sx1[64 * XS], sx2[64 * XS];
    __shared__ float sred[8][64];

    int tid = threadIdx.x, lane = tid & 63, wave = tid >> 6;
    int tile0 = blockIdx.x * 64;
    int sub = lane / LPE, c = lane % LPE;

    // ---- phase A: gather 8 nodes per wave, x1/x2 -> LDS ----
    for (int rr = 0; rr < 8; ++rr) {
        int row = wave * 8 + rr;
        int v = tile0 + row;
        if (v >= nnodes) break;                     // wave-uniform
        int vu = __builtin_amdgcn_readfirstlane(v); // scalar node index
        int beg = rowptr[vu];
        int deg = rowptr[vu + 1] - beg;

        float4 acc = make_float4(0.f, 0.f, 0.f, 0.f);
        for (int kb = 0; kb < deg; kb += 64) {
            int kc = kb + lane;
            bool inr = kc < deg;
            int sv = inr ? (se_s[beg + kc] & 0x1FFFF) : 0;
            float av = inr ? att_s[beg + kc] * nrm_in[sv] : 0.0f;  // fold norm
            int kmax = min(64, deg - kb);
            for (int k0 = 0; k0 < kmax; k0 += U * EP) {
                float a[U];
                const float4* p[U];
                #pragma unroll
                for (int u = 0; u < U; ++u) {
                    int kk = k0 + u * EP + sub;
                    bool val = kk < kmax;
                    int kidx = val ? kk : 0;
                    int ssrc = __shfl(sv, kidx, 64);
                    float aa = __shfl(av, kidx, 64);
                    a[u] = val ? aa : 0.0f;
                    p[u] = (const float4*)(node + (size_t)ssrc * nstride + 4 * c);
                }
                float4 rv[U];
                #pragma unroll
                for (int u = 0; u < U; ++u) rv[u] = *p[u];
                #pragma unroll
                for (int u = 0; u < U; ++u) {
                    acc.x += a[u] * rv[u].x;
                    acc.y += a[u] * rv[u].y;
                    acc.z += a[u] * rv[u].z;
                    acc.w += a[u] * rv[u].w;
                }
            }
        }
        #pragma unroll
        for (int off = LPE; off < 64; off <<= 1) {
            acc.x += __shfl_xor(acc.x, off, 64);
            acc.y += __shfl_xor(acc.y, off, 64);
            acc.z += __shfl_xor(acc.z, off, 64);
            acc.w += __shfl_xor(acc.w, off, 64);
        }
        if (sub == 0) {
            float aiv = ai[vu];
            float rn = nrm_in[vu];
            float4 nv4 = *(const float4*)(node + (size_t)vu * nstride + 4 * c);
            nv4.x *= rn; nv4.y *= rn; nv4.z *= rn; nv4.w *= rn;
            acc.x *= aiv; acc.y *= aiv; acc.z *= aiv; acc.w *= aiv;
            float* p1 = sx1 + row * XS + 4 * c;
            float* p2 = sx2 + row * XS + 4 * c;
            p1[0] = nv4.x + acc.x; p1[1] = nv4.y + acc.y;
            p1[2] = nv4.z + acc.z; p1[3] = nv4.w + acc.w;
            p2[0] = nv4.x * acc.x; p2[1] = nv4.y * acc.y;
            p2[2] = nv4.z * acc.z; p2[3] = nv4.w * acc.w;
        }
    }
    __syncthreads();

    // ---- phase B: dual GEMV, lane = node, 8-way j-split ----
    int jh = __builtin_amdgcn_readfirstlane(wave);   // SGPR wave id
    int j0 = jh * DH;
    int v = tile0 + lane;
    bool act = v < nnodes;

    float acc1[DH], acc2[DH];
    #pragma unroll
    for (int j = 0; j < DH; ++j) { acc1[j] = 0.f; acc2[j] = 0.f; }

    const float* px1 = sx1 + lane * XS;
    const float* px2 = sx2 + lane * XS;
    #pragma unroll 1
    for (int ic = 0; ic < DIN; ic += 8) {
        float x1c[8], x2c[8];
        #pragma unroll
        for (int t = 0; t < 8; ++t) {
            x1c[t] = px1[ic + t];
            x2c[t] = px2[ic + t];
        }
        #pragma unroll
        for (int j = 0; j < DH; ++j) {
            // scalar addresses: args + SGPR j0 + loop constants -> s_load
            const float* w1 = W1 + (size_t)(j0 + j) * DIN + ic;
            const float* w2 = W2 + (size_t)(j0 + j) * DIN + ic;
            #pragma unroll
            for (int t = 0; t < 8; ++t) {
                acc1[j] = fmaf(x1c[t], w1[t], acc1[j]);
                acc2[j] = fmaf(x2c[t], w2[t], acc2[j]);
            }
        }
    }

    float o[DH];
    float ss = 0.0f;
    #pragma unroll
    for (int j = 0; j < DH; ++j) {
        float a1 = acc1[j] + b1[j0 + j];
        a1 = a1 >= 0.0f ? a1 : 0.01f * a1;   // leaky_relu
        float a2 = acc2[j] + b2[j0 + j];
        a2 = a2 >= 0.0f ? a2 : 0.01f * a2;
        o[j] = a1 + a2;
        ss += o[j] * o[j];
    }
    sred[jh][lane] = ss;
    __syncthreads();
    float tot = 0.0f;
    #pragma unroll
    for (int qq = 0; qq < 8; ++qq) tot += sred[qq][lane];
    float nv2 = fmaxf(sqrtf(tot), 1e-12f);
    float inv = 1.0f / nv2;
    if (act) {
        float* po = out + (size_t)v * 240 + out_col + j0;
        if (DH >= 4) {
            #pragma unroll
            for (int j = 0; j < DH; j += 4) {
                float4 st = make_float4(o[j] * inv, o[j + 1] * inv,
                                        o[j + 2] * inv, o[j + 3] * inv);
                *(float4*)(po + j) = st;
            }
        } else {
            #pragma unroll
            for (int j = 0; j < DH; ++j) po[j] = o[j] * inv;
        }
        if (nrm_out && jh == 0) nrm_out[v] = nv2;
    }
}

// Dual GEMV over a 64-node tile per 512-thread block, i-range processed in
// IH=32-dim quarters (for DIN=128) so LDS stays ~19KB (8 blocks/CU). 8 waves
// split j-range; W via s_load; norm via one LDS combine. Layer 0 (reads Nh).
template<int DIN, int DOUT, bool NRM, bool EGO>
__global__ __launch_bounds__(512) void gemm_kernel(
    const float* __restrict__ node, int nstride, const float* __restrict__ nrm_in,
    const float* __restrict__ Nh,
    const float* __restrict__ W1, const float* __restrict__ b1,
    const float* __restrict__ W2, const float* __restrict__ b2,
    float* __restrict__ out, int out_col, float* __restrict__ nrm_out, int nnodes)
{
    constexpr int IH  = (DIN < 32) ? DIN : 32;   // dims per sub-tile
    constexpr int NHV = DIN / IH;                // sub-tiles (4 for DIN=128)
    constexpr int XS  = IH + 1;                  // padded row stride (odd)
    constexpr int CPR = IH / 8;                  // 8-dim chunks per row
    constexpr int DH  = DOUT / 8;                // j-range per wave
    __shared__ float sx1[64 * XS], sx2[64 * XS];
    __shared__ float sred[8][64];

    int tid = threadIdx.x;
    int tile0 = blockIdx.x * 64;
    int lane = tid & 63;
    int jh = __builtin_amdgcn_readfirstlane(tid >> 6);   // SGPR wave id
    int j0 = jh * DH;
    int v = tile0 + lane;
    bool act = v < nnodes;

    float acc1[DH], acc2[DH];
    #pragma unroll
    for (int j = 0; j < DH; ++j) { acc1[j] = 0.f; acc2[j] = 0.f; }

    const float* px1 = sx1 + lane * XS;
    const float* px2 = sx2 + lane * XS;

    #pragma unroll
    for (int h = 0; h < NHV; ++h) {
        const int i0 = h * IH;
        if (h) __syncthreads();      // prior compute done before restage

        // ---- staging (coalesced global, conflict-free LDS writes) ----
        for (int idx = tid; idx < 64 * CPR; idx += 512) {
            int row = idx / CPR, c = idx % CPR;
            int vv = tile0 + row;
            float4 n0 = make_float4(0.f, 0.f, 0.f, 0.f), n1 = n0;
            float4 h0 = n0, h1 = n0;
            if (vv < nnodes) {
                const float* pn = node + (size_t)vv * nstride + i0 + 8 * c;
                const float* ph = Nh + (size_t)vv * DIN + i0 + 8 * c;
                n0 = *(const float4*)pn;
                n1 = *(const float4*)(pn + 4);
                h0 = *(const float4*)ph;
                h1 = *(const float4*)(ph + 4);
                if (EGO) {
                    float* po = out + (size_t)vv * 240 + i0 + 8 * c;
                    *(float4*)po = n0;
                    *(float4*)(po + 4) = n1;
                }
                if (NRM) {
                    float rn = nrm_in[vv];
                    n0.x *= rn; n0.y *= rn; n0.z *= rn; n0.w *= rn;
                    n1.x *= rn; n1.y *= rn; n1.z *= rn; n1.w *= rn;
                }
            }
            float* p1 = sx1 + row * XS + 8 * c;
            float* p2 = sx2 + row * XS + 8 * c;
            p1[0] = n0.x + h0.x; p1[1] = n0.y + h0.y;
            p1[2] = n0.z + h0.z; p1[3] = n0.w + h0.w;
            p1[4] = n1.x + h1.x; p1[5] = n1.y + h1.y;
            p1[6] = n1.z + h1.z; p1[7] = n1.w + h1.w;
            p2[0] = n0.x * h0.x; p2[1] = n0.y * h0.y;
            p2[2] = n0.z * h0.z; p2[3] = n0.w * h0.w;
            p2[4] = n1.x * h1.x; p2[5] = n1.y * h1.y;
            p2[6] = n1.z * h1.z; p2[7] = n1.w * h1.w;
        }
        __syncthreads();

        // ---- dual GEMV accumulate over this sub-tile, lane = node ----
        #pragma unroll 1
        for (int ic = 0; ic < IH; ic += 8) {
            float x1c[8], x2c[8];
            #pragma unroll
            for (int t = 0; t < 8; ++t) {
                x1c[t] = px1[ic + t];
                x2c[t] = px2[ic + t];
            }
            #pragma unroll
            for (int j = 0; j < DH; ++j) {
                // scalar addresses: args + SGPR j0 + loop constants -> s_load
                const float* w1 = W1 + (size_t)(j0 + j) * DIN + i0 + ic;
                const float* w2 = W2 + (size_t)(j0 + j) * DIN + i0 + ic;
                #pragma unroll
                for (int t = 0; t < 8; ++t) {
                    acc1[j] = fmaf(x1c[t], w1[t], acc1[j]);
                    acc2[j] = fmaf(x2c[t], w2[t], acc2[j]);
                }
            }
        }
    }

    float o[DH];
    float ss = 0.0f;
    #pragma unroll
    for (int j = 0; j < DH; ++j) {
        float a1 = acc1[j] + b1[j0 + j];
        a1 = a1 >= 0.0f ? a1 : 0.01f * a1;   // leaky_relu
        float a2 = acc2[j] + b2[j0 + j];
        a2 = a2 >= 0.0f ? a2 : 0.01f * a2;
        o[j] = a1 + a2;
        ss += o[j] * o[j];
    }
    sred[jh][lane] = ss;
    __syncthreads();
    float tot = 0.0f;
    #pragma unroll
    for (int q = 0; q < 8; ++q) tot += sred[q][lane];
    float nv2 = fmaxf(sqrtf(tot), 1e-12f);
    float inv = 1.0f / nv2;
    if (act) {
        float* po = out + (size_t)v * 240 + out_col + j0;
        if (DH >= 4) {
            #pragma unroll
            for (int j = 0; j < DH; j += 4) {
                float4 st = make_float4(o[j] * inv, o[j + 1] * inv,
                                        o[j + 2] * inv, o[j + 3] * inv);
                *(float4*)(po + j) = st;
            }
        } else {
            #pragma unroll
            for (int j = 0; j < DH; ++j) po[j] = o[j] * inv;
        }
        if (nrm_out && jh == 0) nrm_out[v] = nv2;
    }
}

extern "C" void kernel_launch(void* const* d_in, const int* in_sizes, int n_in,
                              void* d_out, int out_size, void* d_ws, size_t ws_size,
                              hipStream_t stream) {
    const float* embed = (const float*)d_in[0];
    const float* rel   = (const float*)d_in[1];
    const float* pw    = (const float*)d_in[2];
    const float* mw    = (const float*)d_in[3];
    const float* W1_0  = (const float*)d_in[4];
    const float* b1_0  = (const float*)d_in[5];
    const float* W2_0  = (const float*)d_in[6];
    const float* b2_0  = (const float*)d_in[7];
    const float* W1_1  = (const float*)d_in[8];
    const float* b1_1  = (const float*)d_in[9];
    const float* W2_1  = (const float*)d_in[10];
    const float* b2_1  = (const float*)d_in[11];
    const float* W1_2  = (const float*)d_in[12];
    const float* b1_2  = (const float*)d_in[13];
    const float* W1_2b = (const float*)d_in[14];
    const float* b2_2  = (const float*)d_in[15];
    const int* src   = (const int*)d_in[16];
    const int* dst   = (const int*)d_in[17];
    const int* etype = (const int*)d_in[18];
    float* out = (float*)d_out;

    const int n = in_sizes[0] / 128;   // 100000
    const int e = in_sizes[16];        // 1000000
    const int r = in_sizes[1] / 192;   // 40

    // workspace (~62 MB), fully rewritten each call
    char* ws = (char*)d_ws;
    float* att_s  = (float*)ws;                        // E (unnormalized exp(s))
    int*   se_s   = (int*)(att_s + e);                 // E (src | etype<<17)
    float* Nh     = (float*)(se_s + e);                // N*128 (layer 0 only)
    int*   rowptr = (int*)(Nh + (size_t)n * 128);      // N+1
    int*   cnt    = rowptr + n + 1;                    // N
    int*   cursor = cnt + n;                           // N
    int*   bsum   = cursor + n;                        // 128
    int*   boff   = bsum + 128;                        // 128
    float* nrm1   = (float*)(boff + 128);              // N
    float* nrm2   = nrm1 + n;                          // N
    float* ai     = nrm2 + n;                          // N (1/den)

    const int NB = (n + 1023) / 1024;   // scan blocks (98)

    hipMemsetAsync(cnt, 0, (size_t)(2 * n) * 4, stream);   // cnt + cursor
    hist_kernel<<<(e + 255) / 256, 256, 0, stream>>>(dst, cnt, e);
    scan_block_kernel<<<NB, 1024, 0, stream>>>(cnt, rowptr, bsum, n);
    scan_tops_kernel<<<1, 64, 0, stream>>>(bsum, boff, NB);
    scan_add_kernel<<<NB, 1024, 0, stream>>>(rowptr, boff, n);
    fill_kernel<<<(e + 255) / 256, 256, 0, stream>>>(src, dst, etype, rowptr,
                                                     cursor, se_s, e);

    int tiles = (n + 63) / 64;          // 1563 node tiles (64 nodes per block)

    // ---- fused: scores + softmax accumulation + layer-0 gather ----
    att_gather_kernel<<<2048, 512, 0, stream>>>(
        embed, rel, pw, mw, se_s, rowptr, att_s, ai, Nh, n, r);

    // ---- layer 0: 128 -> 64, out cols [128,192) + ego copy to cols [0,128) --
    gemm_kernel<128, 64, false, true><<<tiles, 512, 0, stream>>>(
        embed, 128, nullptr, Nh, W1_0, b1_0, W2_0, b2_0, out, 128, nrm1, n);
    // ---- layer 1 fused: 64 -> 32, out cols [192,224) ----
    fused_layer_kernel<64, 32><<<tiles, 512, 0, stream>>>(
        out + 128, 240, nrm1, att_s, se_s, rowptr, ai,
        W1_1, b1_1, W2_1, b2_1, out, 192, nrm2, n);
    // ---- layer 2 fused: 32 -> 16, out cols [224,240) ----
    fused_layer_kernel<32, 16><<<tiles, 512, 0, stream>>>(
        out + 192, 240, nrm2, att_s, se_s, rowptr, ai,
        W1_2, b1_2, W1_2b, b2_2, out, 224, nullptr, n);
}

// Round 20
// 418.290 us; speedup vs baseline: 1.0333x; 1.0333x over previous
//
#include <hip/hip_runtime.h>
#include <math.h>

// ---------------------------------------------------------------------------
// KGAT-hake, round 20: pure revert to round-18 (best measured: 427us).
// r19's quarter-tiling regressed (wave-cap, not LDS, limits residency).
// att_gather: grid 2048, 2-deep pipeline, rel in LDS — at latency floor.
// gemm L0: 64-dim half-tiles (~35KB LDS). Layers 1/2: fused gather+GEMV.
// N=100000 nodes, E=1000000 edges, R=40 rels, out = N x 240 fp32.
// ---------------------------------------------------------------------------

__global__ void hist_kernel(const int* __restrict__ dst, int* __restrict__ cnt,
                            int nedges) {
    int e = blockIdx.x * blockDim.x + threadIdx.x;
    if (e < nedges) atomicAdd(&cnt[dst[e]], 1);
}

// Per-block inclusive scan of cnt -> rowptr[i+1] (block-local) + block sums.
__global__ __launch_bounds__(1024) void scan_block_kernel(
    const int* __restrict__ cnt, int* __restrict__ rowptr,
    int* __restrict__ bsum, int n) {
    __shared__ int swv[16];
    int tid = threadIdx.x, lane = tid & 63, wid = tid >> 6;
    int i = blockIdx.x * 1024 + tid;
    int v = (i < n) ? cnt[i] : 0;
    #pragma unroll
    for (int off = 1; off < 64; off <<= 1) {
        int t = __shfl_up(v, off, 64);
        if (lane >= off) v += t;
    }
    if (lane == 63) swv[wid] = v;
    __syncthreads();
    if (wid == 0) {
        int s = (lane < 16) ? swv[lane] : 0;
        #pragma unroll
        for (int off = 1; off < 16; off <<= 1) {
            int t = __shfl_up(s, off, 64);
            if (lane >= off) s += t;
        }
        if (lane < 16) swv[lane] = s;
    }
    __syncthreads();
    int offv = wid ? swv[wid - 1] : 0;
    if (i < n) rowptr[i + 1] = v + offv;
    if (tid == 1023) bsum[blockIdx.x] = v + offv;
}

// Exclusive scan of up to 128 block sums (one wave, 2 elems/lane).
__global__ __launch_bounds__(64) void scan_tops_kernel(
    const int* __restrict__ bsum, int* __restrict__ boff, int nb) {
    int l = threadIdx.x;
    int a = (2 * l < nb) ? bsum[2 * l] : 0;
    int b = (2 * l + 1 < nb) ? bsum[2 * l + 1] : 0;
    int s = a + b;
    #pragma unroll
    for (int off = 1; off < 64; off <<= 1) {
        int t = __shfl_up(s, off, 64);
        if (l >= off) s += t;
    }
    int excl = s - (a + b);
    if (2 * l < nb) boff[2 * l] = excl;
    if (2 * l + 1 < nb) boff[2 * l + 1] = excl + a;
}

__global__ __launch_bounds__(1024) void scan_add_kernel(
    int* __restrict__ rowptr, const int* __restrict__ boff, int n) {
    int i = blockIdx.x * 1024 + threadIdx.x;
    if (i < n) rowptr[i + 1] += boff[blockIdx.x];
    if (i == 0) rowptr[0] = 0;
}

// Scatter packed src|etype<<17 into dst-sorted CSR slots.
__global__ void fill_kernel(const int* __restrict__ src, const int* __restrict__ dst,
                            const int* __restrict__ etype,
                            const int* __restrict__ rowptr, int* __restrict__ cursor,
                            int* __restrict__ se_s, int nedges) {
    int e = blockIdx.x * blockDim.x + threadIdx.x;
    if (e >= nedges) return;
    int d = dst[e];
    int slot = rowptr[d] + atomicAdd(&cursor[d], 1);
    se_s[slot] = src[e] | (etype[e] << 17);
}

// Fused: HAKE scores + softmax accumulation + layer-0 gather.
// Block: 512 threads; rel coefficients in LDS (stride 196). 8 waves
// grid-stride over nodes; 4 edges/iter x 16 lanes/edge, 2-deep software
// pipeline: group k0+4's t-row loads issue before group k0's compute.
__global__ __launch_bounds__(512) void att_gather_kernel(
    const float* __restrict__ embed, const float* __restrict__ rel,
    const float* __restrict__ pw, const float* __restrict__ mw,
    const int* __restrict__ se_s, const int* __restrict__ rowptr,
    float* __restrict__ att_s, float* __restrict__ ai,
    float* __restrict__ Nh, int nnodes, int nrel)
{
    __shared__ float sRel[40 * 196];
    int tid = threadIdx.x;

    // stage A=|mr|+clamp(br), B=1-clamp(br), P=pr into LDS
    for (int idx = tid; idx < nrel * 64; idx += 512) {
        int r = idx >> 6, d = idx & 63;
        float pr = rel[r * 192 + d];
        float mr = fabsf(rel[r * 192 + 64 + d]);
        float br = rel[r * 192 + 128 + d];
        br = fminf(br, 1.0f);
        br = fmaxf(br, -mr);
        sRel[r * 196 + d]       = mr + br;     // A
        sRel[r * 196 + 64 + d]  = 1.0f - br;   // B
        sRel[r * 196 + 128 + d] = pr;          // P
    }
    __syncthreads();

    const float K = (float)(0.5 * 3.1415926235897933 / 0.21875);  // PI/(2*EMB_RANGE)
    float mwv = mw[0], pwv = pw[0];

    int wave = tid >> 6, lane = tid & 63;
    int g = lane >> 4;            // edge group (4)
    int q = lane & 15;            // dim-slice (16)

    for (int v = blockIdx.x * 8 + wave; v < nnodes; v += gridDim.x * 8) {
        int vu = __builtin_amdgcn_readfirstlane(v);   // scalar node index
        int beg = rowptr[vu];
        int deg = rowptr[vu + 1] - beg;

        const float* hrow = embed + (size_t)vu * 128;
        float4 hp = *(const float4*)(hrow + 4 * q);
        float4 hm = *(const float4*)(hrow + 64 + 4 * q);

        float den = 0.0f;
        float4 accp = make_float4(0.f, 0.f, 0.f, 0.f);
        float4 accm = make_float4(0.f, 0.f, 0.f, 0.f);

        for (int kb = 0; kb < deg; kb += 64) {
            int kchunk = min(64, deg - kb);
            int sev = (lane < kchunk) ? se_s[beg + kb + lane] : 0;  // coalesced

            // ---- pipeline prologue: prefetch group 0 ----
            bool valid0 = g < kchunk;
            int se0 = __shfl(sev, valid0 ? g : 0, 64);
            int r0 = se0 >> 17;
            const float* trow0 = embed + (size_t)(se0 & 0x1FFFF) * 128;
            float4 tp0 = *(const float4*)(trow0 + 4 * q);
            float4 tm0 = *(const float4*)(trow0 + 64 + 4 * q);

            for (int k0 = 0; k0 < kchunk; k0 += 4) {
                // ---- issue next group's loads (independent of compute) ----
                float4 tp1 = tp0, tm1 = tm0;
                int r1 = r0;
                bool valid1 = false;
                if (k0 + 4 < kchunk) {
                    int kn = k0 + 4 + g;
                    valid1 = kn < kchunk;
                    int se1 = __shfl(sev, valid1 ? kn : 0, 64);
                    r1 = se1 >> 17;
                    const float* trow1 = embed + (size_t)(se1 & 0x1FFFF) * 128;
                    tp1 = *(const float4*)(trow1 + 4 * q);
                    tm1 = *(const float4*)(trow1 + 64 + 4 * q);
                }

                // ---- compute current group (tp0/tm0/r0/valid0) ----
                const float* rrow = sRel + r0 * 196;
                float4 A4 = *(const float4*)(rrow + 4 * q);
                float4 B4 = *(const float4*)(rrow + 64 + 4 * q);
                float4 P4 = *(const float4*)(rrow + 128 + 4 * q);

                float pp;
                pp  = fabsf(__sinf((hp.x + P4.x - tp0.x) * K));
                pp += fabsf(__sinf((hp.y + P4.y - tp0.y) * K));
                pp += fabsf(__sinf((hp.z + P4.z - tp0.z) * K));
                pp += fabsf(__sinf((hp.w + P4.w - tp0.w) * K));

                float d0 = hm.x * A4.x - tm0.x * B4.x;
                float d1 = hm.y * A4.y - tm0.y * B4.y;
                float d2 = hm.z * A4.z - tm0.z * B4.z;
                float d3 = hm.w * A4.w - tm0.w * B4.w;
                float qq = (d0 * d0 + d1 * d1) + (d2 * d2 + d3 * d3);

                // reduce pp,qq within the 16-lane group
                #pragma unroll
                for (int off = 1; off < 16; off <<= 1) {
                    pp += __shfl_xor(pp, off, 64);
                    qq += __shfl_xor(qq, off, 64);
                }
                float s = sqrtf(qq) * mwv + pp * pwv;
                float w = valid0 ? __expf(s) : 0.0f;   // s bounded -> no max
                den += w;
                accp.x = fmaf(w, tp0.x, accp.x); accp.y = fmaf(w, tp0.y, accp.y);
                accp.z = fmaf(w, tp0.z, accp.z); accp.w = fmaf(w, tp0.w, accp.w);
                accm.x = fmaf(w, tm0.x, accm.x); accm.y = fmaf(w, tm0.y, accm.y);
                accm.z = fmaf(w, tm0.z, accm.z); accm.w = fmaf(w, tm0.w, accm.w);
                if (valid0 && q == 0) att_s[beg + kb + k0 + g] = w;

                // ---- rotate pipeline ----
                tp0 = tp1; tm0 = tm1; r0 = r1; valid0 = valid1;
            }
        }

        // combine the 4 groups (lane bits 4,5)
        #pragma unroll
        for (int off = 16; off < 64; off <<= 1) {
            accp.x += __shfl_xor(accp.x, off, 64);
            accp.y += __shfl_xor(accp.y, off, 64);
            accp.z += __shfl_xor(accp.z, off, 64);
            accp.w += __shfl_xor(accp.w, off, 64);
            accm.x += __shfl_xor(accm.x, off, 64);
            accm.y += __shfl_xor(accm.y, off, 64);
            accm.z += __shfl_xor(accm.z, off, 64);
            accm.w += __shfl_xor(accm.w, off, 64);
            den += __shfl_xor(den, off, 64);
        }
        float invd = (deg > 0) ? 1.0f / den : 0.0f;
        if (g == 0) {
            float* pn = Nh + (size_t)vu * 128;
            *(float4*)(pn + 4 * q) = make_float4(accp.x * invd, accp.y * invd,
                                                 accp.z * invd, accp.w * invd);
            *(float4*)(pn + 64 + 4 * q) = make_float4(accm.x * invd, accm.y * invd,
                                                      accm.z * invd, accm.w * invd);
            if (q == 0) ai[vu] = invd;
        }
    }
}

// Fused layer 1/2: CSR gather (phase A, wave-per-node, 8 nodes/wave) writes
// x1=(x+Nh), x2=(x*Nh) directly into LDS; phase B = dual GEMV (8-way j-split,
// W via s_load) + leaky_relu + row-normalize. No Nh intermediate.
template<int DIN, int DOUT>
__global__ __launch_bounds__(512) void fused_layer_kernel(
    const float* __restrict__ node, int nstride, const float* __restrict__ nrm_in,
    const float* __restrict__ att_s, const int* __restrict__ se_s,
    const int* __restrict__ rowptr, const float* __restrict__ ai,
    const float* __restrict__ W1, const float* __restrict__ b1,
    const float* __restrict__ W2, const float* __restrict__ b2,
    float* __restrict__ out, int out_col, float* __restrict__ nrm_out, int nnodes)
{
    constexpr int XS  = DIN + 1;     // padded LDS row stride (odd)
    constexpr int LPE = DIN / 4;     // lanes per edge row
    constexpr int EP  = 64 / LPE;    // edges in parallel
    constexpr int U   = 4;           // gather unroll depth
    constexpr int DH  = DOUT / 8;    // j-range per wave
    __shared__ float sx1[64 * XS], sx2[64 * XS];
    __shared__ float sred[8][64];

    int tid = threadIdx.x, lane = tid & 63, wave = tid >> 6;
    int tile0 = blockIdx.x * 64;
    int sub = lane / LPE, c = lane % LPE;

    // ---- phase A: gather 8 nodes per wave, x1/x2 -> LDS ----
    for (int rr = 0; rr < 8; ++rr) {
        int row = wave * 8 + rr;
        int v = tile0 + row;
        if (v >= nnodes) break;                     // wave-uniform
        int vu = __builtin_amdgcn_readfirstlane(v); // scalar node index
        int beg = rowptr[vu];
        int deg = rowptr[vu + 1] - beg;

        float4 acc = make_float4(0.f, 0.f, 0.f, 0.f);
        for (int kb = 0; kb < deg; kb += 64) {
            int kc = kb + lane;
            bool inr = kc < deg;
            int sv = inr ? (se_s[beg + kc] & 0x1FFFF) : 0;
            float av = inr ? att_s[beg + kc] * nrm_in[sv] : 0.0f;  // fold norm
            int kmax = min(64, deg - kb);
            for (int k0 = 0; k0 < kmax; k0 += U * EP) {
                float a[U];
                const float4* p[U];
                #pragma unroll
                for (int u = 0; u < U; ++u) {
                    int kk = k0 + u * EP + sub;
                    bool val = kk < kmax;
                    int kidx = val ? kk : 0;
                    int ssrc = __shfl(sv, kidx, 64);
                    float aa = __shfl(av, kidx, 64);
                    a[u] = val ? aa : 0.0f;
                    p[u] = (const float4*)(node + (size_t)ssrc * nstride + 4 * c);
                }
                float4 rv[U];
                #pragma unroll
                for (int u = 0; u < U; ++u) rv[u] = *p[u];
                #pragma unroll
                for (int u = 0; u < U; ++u) {
                    acc.x += a[u] * rv[u].x;
                    acc.y += a[u] * rv[u].y;
                    acc.z += a[u] * rv[u].z;
                    acc.w += a[u] * rv[u].w;
                }
            }
        }
        #pragma unroll
        for (int off = LPE; off < 64; off <<= 1) {
            acc.x += __shfl_xor(acc.x, off, 64);
            acc.y += __shfl_xor(acc.y, off, 64);
            acc.z += __shfl_xor(acc.z, off, 64);
            acc.w += __shfl_xor(acc.w, off, 64);
        }
        if (sub == 0) {
            float aiv = ai[vu];
            float rn = nrm_in[vu];
            float4 nv4 = *(const float4*)(node + (size_t)vu * nstride + 4 * c);
            nv4.x *= rn; nv4.y *= rn; nv4.z *= rn; nv4.w *= rn;
            acc.x *= aiv; acc.y *= aiv; acc.z *= aiv; acc.w *= aiv;
            float* p1 = sx1 + row * XS + 4 * c;
            float* p2 = sx2 + row * XS + 4 * c;
            p1[0] = nv4.x + acc.x; p1[1] = nv4.y + acc.y;
            p1[2] = nv4.z + acc.z; p1[3] = nv4.w + acc.w;
            p2[0] = nv4.x * acc.x; p2[1] = nv4.y * acc.y;
            p2[2] = nv4.z * acc.z; p2[3] = nv4.w * acc.w;
        }
    }
    __syncthreads();

    // ---- phase B: dual GEMV, lane = node, 8-way j-split ----
    int jh = __builtin_amdgcn_readfirstlane(wave);   // SGPR wave id
    int j0 = jh * DH;
    int v = tile0 + lane;
    bool act = v < nnodes;

    float acc1[DH], acc2[DH];
    #pragma unroll
    for (int j = 0; j < DH; ++j) { acc1[j] = 0.f; acc2[j] = 0.f; }

    const float* px1 = sx1 + lane * XS;
    const float* px2 = sx2 + lane * XS;
    #pragma unroll 1
    for (int ic = 0; ic < DIN; ic += 8) {
        float x1c[8], x2c[8];
        #pragma unroll
        for (int t = 0; t < 8; ++t) {
            x1c[t] = px1[ic + t];
            x2c[t] = px2[ic + t];
        }
        #pragma unroll
        for (int j = 0; j < DH; ++j) {
            // scalar addresses: args + SGPR j0 + loop constants -> s_load
            const float* w1 = W1 + (size_t)(j0 + j) * DIN + ic;
            const float* w2 = W2 + (size_t)(j0 + j) * DIN + ic;
            #pragma unroll
            for (int t = 0; t < 8; ++t) {
                acc1[j] = fmaf(x1c[t], w1[t], acc1[j]);
                acc2[j] = fmaf(x2c[t], w2[t], acc2[j]);
            }
        }
    }

    float o[DH];
    float ss = 0.0f;
    #pragma unroll
    for (int j = 0; j < DH; ++j) {
        float a1 = acc1[j] + b1[j0 + j];
        a1 = a1 >= 0.0f ? a1 : 0.01f * a1;   // leaky_relu
        float a2 = acc2[j] + b2[j0 + j];
        a2 = a2 >= 0.0f ? a2 : 0.01f * a2;
        o[j] = a1 + a2;
        ss += o[j] * o[j];
    }
    sred[jh][lane] = ss;
    __syncthreads();
    float tot = 0.0f;
    #pragma unroll
    for (int qq = 0; qq < 8; ++qq) tot += sred[qq][lane];
    float nv2 = fmaxf(sqrtf(tot), 1e-12f);
    float inv = 1.0f / nv2;
    if (act) {
        float* po = out + (size_t)v * 240 + out_col + j0;
        if (DH >= 4) {
            #pragma unroll
            for (int j = 0; j < DH; j += 4) {
                float4 st = make_float4(o[j] * inv, o[j + 1] * inv,
                                        o[j + 2] * inv, o[j + 3] * inv);
                *(float4*)(po + j) = st;
            }
        } else {
            #pragma unroll
            for (int j = 0; j < DH; ++j) po[j] = o[j] * inv;
        }
        if (nrm_out && jh == 0) nrm_out[v] = nv2;
    }
}

// Dual GEMV over a 64-node tile per 512-thread block, i-range processed in
// IH=64-dim halves so LDS stays ~33KB. 8 waves split j-range; W via s_load;
// norm via one LDS combine. Used for layer 0 (reads Nh).
template<int DIN, int DOUT, bool NRM, bool EGO>
__global__ __launch_bounds__(512) void gemm_kernel(
    const float* __restrict__ node, int nstride, const float* __restrict__ nrm_in,
    const float* __restrict__ Nh,
    const float* __restrict__ W1, const float* __restrict__ b1,
    const float* __restrict__ W2, const float* __restrict__ b2,
    float* __restrict__ out, int out_col, float* __restrict__ nrm_out, int nnodes)
{
    constexpr int IH  = (DIN < 64) ? DIN : 64;   // dims per half
    constexpr int NHV = DIN / IH;                // halves (1 or 2)
    constexpr int XS  = IH + 1;                  // padded row stride (odd)
    constexpr int CPR = IH / 8;                  // 8-dim chunks per row
    constexpr int DH  = DOUT / 8;                // j-range per wave
    __shared__ float sx1[64 * XS], sx2[64 * XS];
    __shared__ float sred[8][64];

    int tid = threadIdx.x;
    int tile0 = blockIdx.x * 64;
    int lane = tid & 63;
    int jh = __builtin_amdgcn_readfirstlane(tid >> 6);   // SGPR wave id
    int j0 = jh * DH;
    int v = tile0 + lane;
    bool act = v < nnodes;

    float acc1[DH], acc2[DH];
    #pragma unroll
    for (int j = 0; j < DH; ++j) { acc1[j] = 0.f; acc2[j] = 0.f; }

    const float* px1 = sx1 + lane * XS;
    const float* px2 = sx2 + lane * XS;

    #pragma unroll
    for (int h = 0; h < NHV; ++h) {
        const int i0 = h * IH;
        if (h) __syncthreads();      // prior compute done before restage

        // ---- staging (coalesced global, scalar conflict-free LDS writes) ----
        for (int idx = tid; idx < 64 * CPR; idx += 512) {
            int row = idx / CPR, c = idx % CPR;
            int vv = tile0 + row;
            float4 n0 = make_float4(0.f, 0.f, 0.f, 0.f), n1 = n0;
            float4 h0 = n0, h1 = n0;
            if (vv < nnodes) {
                const float* pn = node + (size_t)vv * nstride + i0 + 8 * c;
                const float* ph = Nh + (size_t)vv * DIN + i0 + 8 * c;
                n0 = *(const float4*)pn;
                n1 = *(const float4*)(pn + 4);
                h0 = *(const float4*)ph;
                h1 = *(const float4*)(ph + 4);
                if (EGO) {
                    float* po = out + (size_t)vv * 240 + i0 + 8 * c;
                    *(float4*)po = n0;
                    *(float4*)(po + 4) = n1;
                }
                if (NRM) {
                    float rn = nrm_in[vv];
                    n0.x *= rn; n0.y *= rn; n0.z *= rn; n0.w *= rn;
                    n1.x *= rn; n1.y *= rn; n1.z *= rn; n1.w *= rn;
                }
            }
            float* p1 = sx1 + row * XS + 8 * c;
            float* p2 = sx2 + row * XS + 8 * c;
            p1[0] = n0.x + h0.x; p1[1] = n0.y + h0.y;
            p1[2] = n0.z + h0.z; p1[3] = n0.w + h0.w;
            p1[4] = n1.x + h1.x; p1[5] = n1.y + h1.y;
            p1[6] = n1.z + h1.z; p1[7] = n1.w + h1.w;
            p2[0] = n0.x * h0.x; p2[1] = n0.y * h0.y;
            p2[2] = n0.z * h0.z; p2[3] = n0.w * h0.w;
            p2[4] = n1.x * h1.x; p2[5] = n1.y * h1.y;
            p2[6] = n1.z * h1.z; p2[7] = n1.w * h1.w;
        }
        __syncthreads();

        // ---- dual GEMV accumulate over this half, lane = node ----
        #pragma unroll 1
        for (int ic = 0; ic < IH; ic += 8) {
            float x1c[8], x2c[8];
            #pragma unroll
            for (int t = 0; t < 8; ++t) {
                x1c[t] = px1[ic + t];
                x2c[t] = px2[ic + t];
            }
            #pragma unroll
            for (int j = 0; j < DH; ++j) {
                // scalar addresses: args + SGPR j0 + loop constants -> s_load
                const float* w1 = W1 + (size_t)(j0 + j) * DIN + i0 + ic;
                const float* w2 = W2 + (size_t)(j0 + j) * DIN + i0 + ic;
                #pragma unroll
                for (int t = 0; t < 8; ++t) {
                    acc1[j] = fmaf(x1c[t], w1[t], acc1[j]);
                    acc2[j] = fmaf(x2c[t], w2[t], acc2[j]);
                }
            }
        }
    }

    float o[DH];
    float ss = 0.0f;
    #pragma unroll
    for (int j = 0; j < DH; ++j) {
        float a1 = acc1[j] + b1[j0 + j];
        a1 = a1 >= 0.0f ? a1 : 0.01f * a1;   // leaky_relu
        float a2 = acc2[j] + b2[j0 + j];
        a2 = a2 >= 0.0f ? a2 : 0.01f * a2;
        o[j] = a1 + a2;
        ss += o[j] * o[j];
    }
    sred[jh][lane] = ss;
    __syncthreads();
    float tot = 0.0f;
    #pragma unroll
    for (int q = 0; q < 8; ++q) tot += sred[q][lane];
    float nv2 = fmaxf(sqrtf(tot), 1e-12f);
    float inv = 1.0f / nv2;
    if (act) {
        float* po = out + (size_t)v * 240 + out_col + j0;
        if (DH >= 4) {
            #pragma unroll
            for (int j = 0; j < DH; j += 4) {
                float4 st = make_float4(o[j] * inv, o[j + 1] * inv,
                                        o[j + 2] * inv, o[j + 3] * inv);
                *(float4*)(po + j) = st;
            }
        } else {
            #pragma unroll
            for (int j = 0; j < DH; ++j) po[j] = o[j] * inv;
        }
        if (nrm_out && jh == 0) nrm_out[v] = nv2;
    }
}

extern "C" void kernel_launch(void* const* d_in, const int* in_sizes, int n_in,
                              void* d_out, int out_size, void* d_ws, size_t ws_size,
                              hipStream_t stream) {
    const float* embed = (const float*)d_in[0];
    const float* rel   = (const float*)d_in[1];
    const float* pw    = (const float*)d_in[2];
    const float* mw    = (const float*)d_in[3];
    const float* W1_0  = (const float*)d_in[4];
    const float* b1_0  = (const float*)d_in[5];
    const float* W2_0  = (const float*)d_in[6];
    const float* b2_0  = (const float*)d_in[7];
    const float* W1_1  = (const float*)d_in[8];
    const float* b1_1  = (const float*)d_in[9];
    const float* W2_1  = (const float*)d_in[10];
    const float* b2_1  = (const float*)d_in[11];
    const float* W1_2  = (const float*)d_in[12];
    const float* b1_2  = (const float*)d_in[13];
    const float* W1_2b = (const float*)d_in[14];
    const float* b2_2  = (const float*)d_in[15];
    const int* src   = (const int*)d_in[16];
    const int* dst   = (const int*)d_in[17];
    const int* etype = (const int*)d_in[18];
    float* out = (float*)d_out;

    const int n = in_sizes[0] / 128;   // 100000
    const int e = in_sizes[16];        // 1000000
    const int r = in_sizes[1] / 192;   // 40

    // workspace (~62 MB), fully rewritten each call
    char* ws = (char*)d_ws;
    float* att_s  = (float*)ws;                        // E (unnormalized exp(s))
    int*   se_s   = (int*)(att_s + e);                 // E (src | etype<<17)
    float* Nh     = (float*)(se_s + e);                // N*128 (layer 0 only)
    int*   rowptr = (int*)(Nh + (size_t)n * 128);      // N+1
    int*   cnt    = rowptr + n + 1;                    // N
    int*   cursor = cnt + n;                           // N
    int*   bsum   = cursor + n;                        // 128
    int*   boff   = bsum + 128;                        // 128
    float* nrm1   = (float*)(boff + 128);              // N
    float* nrm2   = nrm1 + n;                          // N
    float* ai     = nrm2 + n;                          // N (1/den)

    const int NB = (n + 1023) / 1024;   // scan blocks (98)

    hipMemsetAsync(cnt, 0, (size_t)(2 * n) * 4, stream);   // cnt + cursor
    hist_kernel<<<(e + 255) / 256, 256, 0, stream>>>(dst, cnt, e);
    scan_block_kernel<<<NB, 1024, 0, stream>>>(cnt, rowptr, bsum, n);
    scan_tops_kernel<<<1, 64, 0, stream>>>(bsum, boff, NB);
    scan_add_kernel<<<NB, 1024, 0, stream>>>(rowptr, boff, n);
    fill_kernel<<<(e + 255) / 256, 256, 0, stream>>>(src, dst, etype, rowptr,
                                                     cursor, se_s, e);

    int tiles = (n + 63) / 64;          // 1563 node tiles (64 nodes per block)

    // ---- fused: scores + softmax accumulation + layer-0 gather ----
    att_gather_kernel<<<2048, 512, 0, stream>>>(
        embed, rel, pw, mw, se_s, rowptr, att_s, ai, Nh, n, r);

    // ---- layer 0: 128 -> 64, out cols [128,192) + ego copy to cols [0,128) --
    gemm_kernel<128, 64, false, true><<<tiles, 512, 0, stream>>>(
        embed, 128, nullptr, Nh, W1_0, b1_0, W2_0, b2_0, out, 128, nrm1, n);
    // ---- layer 1 fused: 64 -> 32, out cols [192,224) ----
    fused_layer_kernel<64, 32><<<tiles, 512, 0, stream>>>(
        out + 128, 240, nrm1, att_s, se_s, rowptr, ai,
        W1_1, b1_1, W2_1, b2_1, out, 192, nrm2, n);
    // ---- layer 2 fused: 32 -> 16, out cols [224,240) ----
    fused_layer_kernel<32, 16><<<tiles, 512, 0, stream>>>(
        out + 192, 240, nrm2, att_s, se_s, rowptr, ai,
        W1_2, b1_2, W1_2b, b2_2, out, 224, nullptr, n);
}